// Round 6
// baseline (267.780 us; speedup 1.0000x reference)
//
#include <hip/hip_runtime.h>

#define BB 16
#define SS 512
#define KIN 512
#define H 256

typedef float v2f __attribute__((ext_vector_type(2)));

constexpr float DECAY = 0.951229424500714f;    // exp(-1/20), both tau=20
constexpr float OMD   = 0.048770575499286f;    // 1 - exp(-1/20)
constexpr float LR    = 0.01f;

__device__ __forceinline__ float fast_tanh(float x) {
    float e = __expf(2.f * x);
    return 1.f - __fdividef(2.f, e + 1.f);
}

// Packed f32 (double-rate on CDNA) forced via asm.
__device__ __forceinline__ v2f pk_mul(v2f a, v2f b) {
    v2f d; asm("v_pk_mul_f32 %0, %1, %2" : "=v"(d) : "v"(a), "v"(b)); return d;
}
__device__ __forceinline__ v2f pk_fma(v2f a, v2f b, v2f c) {
    v2f d; asm("v_pk_fma_f32 %0, %1, %2, %3" : "=v"(d) : "v"(a), "v"(b), "v"(c)); return d;
}

// Half-wave (32-lane) sums, all on the VALU/SALU pipes (verified round 3):
// row_shr prefix 1,2,4,8 + row_bcast15 (rows 1,3) -> lane31/63 hold half sums.
__device__ __forceinline__ void half_sum32(float x, float& s_lo, float& s_hi) {
    int t;
    t = __builtin_amdgcn_update_dpp(0, __float_as_int(x), 0x111, 0xf, 0xf, false);
    x += __int_as_float(t);
    t = __builtin_amdgcn_update_dpp(0, __float_as_int(x), 0x112, 0xf, 0xf, false);
    x += __int_as_float(t);
    t = __builtin_amdgcn_update_dpp(0, __float_as_int(x), 0x114, 0xf, 0xf, false);
    x += __int_as_float(t);
    t = __builtin_amdgcn_update_dpp(0, __float_as_int(x), 0x118, 0xf, 0xf, false);
    x += __int_as_float(t);
    t = __builtin_amdgcn_update_dpp(0, __float_as_int(x), 0x142, 0xa, 0xf, false);
    x += __int_as_float(t);
    s_lo = __int_as_float(__builtin_amdgcn_readlane(__float_as_int(x), 31));
    s_hi = __int_as_float(__builtin_amdgcn_readlane(__float_as_int(x), 63));
}

// i = x @ W^T. ik half (n<256) -> ik_out[b*512+s][256]; iv half -> iv_t[b][row][s].
__global__ __launch_bounds__(256) void gemm_xwT(const float* __restrict__ X,
                                                const float* __restrict__ W,
                                                float* __restrict__ ik_out,
                                                float* __restrict__ iv_t) {
    __shared__ float As[16][68];
    __shared__ float Bs[16][68];
    const int m0 = blockIdx.y * 64;
    const int n0 = blockIdx.x * 64;
    const int tid = threadIdx.x;
    const int r  = tid >> 2;
    const int cg = tid & 3;
    const int tx = tid & 15;
    const int ty = tid >> 4;
    float acc[4][4] = {};
    for (int k0 = 0; k0 < KIN; k0 += 16) {
        float4 av = *(const float4*)&X[(size_t)(m0 + r) * KIN + k0 + cg * 4];
        float4 bv = *(const float4*)&W[(size_t)(n0 + r) * KIN + k0 + cg * 4];
        __syncthreads();
        As[cg*4+0][r] = av.x; As[cg*4+1][r] = av.y; As[cg*4+2][r] = av.z; As[cg*4+3][r] = av.w;
        Bs[cg*4+0][r] = bv.x; Bs[cg*4+1][r] = bv.y; Bs[cg*4+2][r] = bv.z; Bs[cg*4+3][r] = bv.w;
        __syncthreads();
#pragma unroll
        for (int kk = 0; kk < 16; ++kk) {
            float4 a = *(const float4*)&As[kk][ty * 4];
            float4 b = *(const float4*)&Bs[kk][tx * 4];
            float ar[4] = {a.x, a.y, a.z, a.w};
            float br[4] = {b.x, b.y, b.z, b.w};
#pragma unroll
            for (int i = 0; i < 4; ++i)
#pragma unroll
                for (int j = 0; j < 4; ++j) acc[i][j] += ar[i] * br[j];
        }
    }
    if (n0 < 256) {
#pragma unroll
        for (int i = 0; i < 4; ++i) {
            float4 o = make_float4(acc[i][0], acc[i][1], acc[i][2], acc[i][3]);
            *(float4*)&ik_out[(size_t)(m0 + ty * 4 + i) * 256 + n0 + tx * 4] = o;
        }
    } else {
        const int b  = m0 >> 9;
        const int s0 = (m0 & 511) + ty * 4;
#pragma unroll
        for (int j = 0; j < 4; ++j) {
            float4 o = make_float4(acc[0][j], acc[1][j], acc[2][j], acc[3][j]);
            *(float4*)&iv_t[((size_t)b * H + (n0 - 256 + tx * 4 + j)) * SS + s0] = o;
        }
    }
}

// Per (b, col): scan kv, write key only. 32-deep prefetch.
__global__ __launch_bounds__(64) void key_scan(const float* __restrict__ ik,
                                               float* __restrict__ keys) {
    const int idx = blockIdx.x * 64 + threadIdx.x;   // 0..4095
    const int b   = idx >> 8;
    const int col = idx & 255;
    const float* c  = ik + (size_t)b * SS * 256 + col;
    float* ko = keys + (size_t)b * SS * H + col;
    float kv = 0.f;
    constexpr int D = 32;
    float ib[D];
#pragma unroll
    for (int j = 0; j < D; ++j) ib[j] = c[(size_t)j * 256];
    for (int t = 0; t < SS; t += D) {
#pragma unroll
        for (int j = 0; j < D; ++j) {
            float v = ib[j];
            int tn = t + D + j; if (tn > SS - 1) tn = SS - 1;
            ib[j] = c[(size_t)tn * 256];
            kv = DECAY * kv + v;
            ko[(size_t)(t + j) * H] = fast_tanh(kv);
        }
    }
}

// ksum[b][t] = 0.2 * sum_j keys[b][t][j]. One wave per (b,t).
__global__ __launch_bounds__(256) void ksum_kernel(const float* __restrict__ keys,
                                                   float* __restrict__ ksum) {
    const int gwave = (blockIdx.x * 256 + threadIdx.x) >> 6;  // 0..8191
    const int lane  = threadIdx.x & 63;
    const int b = gwave >> 9;
    const int t = gwave & 511;
    float4 k = *(const float4*)&keys[((size_t)b * SS + t) * H + lane * 4];
    float s = k.x + k.y + k.z + k.w;
#pragma unroll
    for (int off = 1; off < 64; off <<= 1) s += __shfl_xor(s, off);
    if (lane == 0) ksum[(size_t)b * SS + t] = 0.2f * s;
}

// iv_t[b][row][t] += ksum[b][t] for all rows.
__global__ __launch_bounds__(128) void fold_kernel(const float* __restrict__ ksum,
                                                   float* __restrict__ iv_t) {
    const int b   = blockIdx.x >> 8;
    const int row = blockIdx.x & 255;
    const int t   = threadIdx.x * 4;
    float4 ks = *(const float4*)&ksum[(size_t)b * SS + t];
    float* p = &iv_t[((size_t)b * H + row) * SS + t];
    float4 iv = *(const float4*)p;
    iv.x += ks.x; iv.y += ks.y; iv.z += ks.z; iv.w += ks.w;
    *(float4*)p = iv;
}

// 2 mem-rows per wave (32 lanes/row, 8 cols/lane), u = 1-mem transform,
// packed-f32 asm, marching pointers, peeled tail, no LDS-pipe ops.
__global__ __launch_bounds__(256) void value_scan(const float* __restrict__ keys,
                                                  const float* __restrict__ iv_t,
                                                  float* __restrict__ mem_out,
                                                  float* __restrict__ vals) {
    const int tid  = threadIdx.x;
    const int wave = tid >> 6;
    const int lane = tid & 63;
    const int half = lane >> 5;
    const int sub  = lane & 31;
    const int b    = blockIdx.x & 15;     // XCD swizzle: batch-mates share an XCD
    const int rg   = blockIdx.x >> 4;
    const int row  = rg * 8 + wave * 2 + half;
    const int so   = sub * 8;

    const float* kp  = keys + (size_t)b * SS * H + so;       // marching
    const float* ivp = iv_t + ((size_t)b * H + row) * SS;    // marching
    float* vp = vals + (size_t)b * SS * H + row;             // marching, masked

    const v2f DEC2 = {DECAY, DECAY};
    const v2f OMD2 = {OMD, OMD};

    v2f u[4]   = {{1.f,1.f},{1.f,1.f},{1.f,1.f},{1.f,1.f}};
    v2f ktr[4] = {{0.f,0.f},{0.f,0.f},{0.f,0.f},{0.f,0.f}};
    float vv = 0.f, vt = 0.f;

    // key ring: 8 steps deep, loaded as pair-aligned v2f
    v2f kR[8][4];
#pragma unroll
    for (int j = 0; j < 8; ++j)
#pragma unroll
        for (int q = 0; q < 4; ++q)
            kR[j][q] = *(const v2f*)(kp + (size_t)j * H + q * 2);
    kp += 8 * H;                       // -> step 8

    float4 ivc0 = *(const float4*)(ivp);      // steps 0-3 (with 0.2*Ksum folded)
    float4 ivc1 = *(const float4*)(ivp + 4);  // steps 4-7
    ivp += 8;

#define VS_STEP(J, RELOAD, KOFF)                                               \
    {                                                                          \
        v2f kc0 = kR[J][0], kc1 = kR[J][1], kc2 = kR[J][2], kc3 = kR[J][3];    \
        if (RELOAD) {                                                          \
            kR[J][0] = *(const v2f*)(kp + (KOFF) * H + 0);                     \
            kR[J][1] = *(const v2f*)(kp + (KOFF) * H + 2);                     \
            kR[J][2] = *(const v2f*)(kp + (KOFF) * H + 4);                     \
            kR[J][3] = *(const v2f*)(kp + (KOFF) * H + 6);                     \
        }                                                                      \
        v2f p2 = pk_mul(u[0], kc0);                                            \
        p2 = pk_fma(u[1], kc1, p2);                                            \
        p2 = pk_fma(u[2], kc2, p2);                                            \
        p2 = pk_fma(u[3], kc3, p2);                                            \
        float slo, shi;                                                        \
        half_sum32(p2.x + p2.y, slo, shi);                                     \
        float ps = half ? shi : slo;                                           \
        float civ = (J) < 4 ? ((J)==0?ivc0.x:(J)==1?ivc0.y:(J)==2?ivc0.z:ivc0.w)\
                            : ((J)==4?ivc1.x:(J)==5?ivc1.y:(J)==6?ivc1.z:ivc1.w);\
        vv = DECAY * vv + civ;                                                 \
        vv = __builtin_fmaf(-0.2f, ps, vv);                                    \
        float valv = fast_tanh(vv);                                            \
        vt = DECAY * vt + OMD * valv;                                          \
        if (sub == 0) vp[(size_t)((J) & 3) * H] = valv;                        \
        float an = -LR * vt;                                                   \
        v2f an2 = {an, an};                                                    \
        ktr[0] = pk_fma(DEC2, ktr[0], pk_mul(OMD2, kc0));                      \
        ktr[1] = pk_fma(DEC2, ktr[1], pk_mul(OMD2, kc1));                      \
        ktr[2] = pk_fma(DEC2, ktr[2], pk_mul(OMD2, kc2));                      \
        ktr[3] = pk_fma(DEC2, ktr[3], pk_mul(OMD2, kc3));                      \
        u[0] = pk_fma(pk_mul(an2, ktr[0]), u[0], u[0]);                        \
        u[1] = pk_fma(pk_mul(an2, ktr[1]), u[1], u[1]);                        \
        u[2] = pk_fma(pk_mul(an2, ktr[2]), u[2], u[2]);                        \
        u[3] = pk_fma(pk_mul(an2, ktr[3]), u[3], u[3]);                        \
    }

    for (int t0 = 0; t0 < SS - 8; t0 += 8) {
        float4 ivn0 = *(const float4*)(ivp);      // steps t0+8..t0+11
        float4 ivn1 = *(const float4*)(ivp + 4);  // steps t0+12..t0+15
        ivp += 8;
        VS_STEP(0, true, 0) VS_STEP(1, true, 1) VS_STEP(2, true, 2) VS_STEP(3, true, 3)
        kp += 4 * H; vp += 4 * H;
        VS_STEP(4, true, 0) VS_STEP(5, true, 1) VS_STEP(6, true, 2) VS_STEP(7, true, 3)
        kp += 4 * H; vp += 4 * H;
        ivc0 = ivn0; ivc1 = ivn1;
    }
    // peeled last tile: steps SS-8..SS-1, no reloads
    VS_STEP(0, false, 0) VS_STEP(1, false, 0) VS_STEP(2, false, 0) VS_STEP(3, false, 0)
    vp += 4 * H;
    VS_STEP(4, false, 0) VS_STEP(5, false, 0) VS_STEP(6, false, 0) VS_STEP(7, false, 0)
#undef VS_STEP

    float* mo = &mem_out[((size_t)b * H + row) * H + so];
    *(float4*)&mo[0] = make_float4(1.f - u[0].x, 1.f - u[0].y, 1.f - u[1].x, 1.f - u[1].y);
    *(float4*)&mo[4] = make_float4(1.f - u[2].x, 1.f - u[2].y, 1.f - u[3].x, 1.f - u[3].y);
}

extern "C" void kernel_launch(void* const* d_in, const int* in_sizes, int n_in,
                              void* d_out, int out_size, void* d_ws, size_t ws_size,
                              hipStream_t stream) {
    const float* x = (const float*)d_in[0];   // [B, S, IN] f32
    const float* W = (const float*)d_in[1];   // [2H, IN] f32
    float* out = (float*)d_out;
    float* mem_out = out;                               // [B, H, H]
    float* keys = out + (size_t)BB * H * H;             // [B, S, H]
    float* vals = keys + (size_t)BB * SS * H;           // [B, S, H]
    float* ik   = (float*)d_ws;                         // [B*S, 256]  8 MB
    float* iv_t = ik + (size_t)BB * SS * 256;           // [B, H, S]   8 MB
    float* ksum = ik;                                   // reuse ik (dead after key_scan)

    dim3 gb(8, 128);  // N/64, M/64
    gemm_xwT<<<gb, 256, 0, stream>>>(x, W, ik, iv_t);
    key_scan<<<64, 64, 0, stream>>>(ik, keys);
    ksum_kernel<<<2048, 256, 0, stream>>>(keys, ksum);
    fold_kernel<<<4096, 128, 0, stream>>>(ksum, iv_t);
    value_scan<<<512, 256, 0, stream>>>(keys, iv_t, mem_out, vals);
}

// Round 7
// 255.062 us; speedup vs baseline: 1.0499x; 1.0499x over previous
//
#include <hip/hip_runtime.h>

#define BB 16
#define SS 512
#define KIN 512
#define H 256

typedef float v2f __attribute__((ext_vector_type(2)));

constexpr float DECAY = 0.951229424500714f;    // exp(-1/20), both tau=20
constexpr float OMD   = 0.048770575499286f;    // 1 - exp(-1/20)
constexpr float LR    = 0.01f;

__device__ __forceinline__ float fast_tanh(float x) {
    float e = __expf(2.f * x);
    return 1.f - __fdividef(2.f, e + 1.f);
}

// Packed f32 (double-rate on CDNA) forced via asm.
__device__ __forceinline__ v2f pk_mul(v2f a, v2f b) {
    v2f d; asm("v_pk_mul_f32 %0, %1, %2" : "=v"(d) : "v"(a), "v"(b)); return d;
}
__device__ __forceinline__ v2f pk_fma(v2f a, v2f b, v2f c) {
    v2f d; asm("v_pk_fma_f32 %0, %1, %2, %3" : "=v"(d) : "v"(a), "v"(b), "v"(c)); return d;
}

// Half-wave (32-lane) sums via DPP prefix + row_bcast15; lane31/63 hold sums.
__device__ __forceinline__ void half_sum32(float x, float& s_lo, float& s_hi) {
    int t;
    t = __builtin_amdgcn_update_dpp(0, __float_as_int(x), 0x111, 0xf, 0xf, false);
    x += __int_as_float(t);
    t = __builtin_amdgcn_update_dpp(0, __float_as_int(x), 0x112, 0xf, 0xf, false);
    x += __int_as_float(t);
    t = __builtin_amdgcn_update_dpp(0, __float_as_int(x), 0x114, 0xf, 0xf, false);
    x += __int_as_float(t);
    t = __builtin_amdgcn_update_dpp(0, __float_as_int(x), 0x118, 0xf, 0xf, false);
    x += __int_as_float(t);
    t = __builtin_amdgcn_update_dpp(0, __float_as_int(x), 0x142, 0xa, 0xf, false);
    x += __int_as_float(t);
    s_lo = __int_as_float(__builtin_amdgcn_readlane(__float_as_int(x), 31));
    s_hi = __int_as_float(__builtin_amdgcn_readlane(__float_as_int(x), 63));
}

// i = x @ W^T. ik half (n<256) -> ik_out[b*512+s][256]; iv half -> iv_t[b][row][s].
__global__ __launch_bounds__(256) void gemm_xwT(const float* __restrict__ X,
                                                const float* __restrict__ W,
                                                float* __restrict__ ik_out,
                                                float* __restrict__ iv_t) {
    __shared__ float As[16][68];
    __shared__ float Bs[16][68];
    const int m0 = blockIdx.y * 64;
    const int n0 = blockIdx.x * 64;
    const int tid = threadIdx.x;
    const int r  = tid >> 2;
    const int cg = tid & 3;
    const int tx = tid & 15;
    const int ty = tid >> 4;
    float acc[4][4] = {};
    for (int k0 = 0; k0 < KIN; k0 += 16) {
        float4 av = *(const float4*)&X[(size_t)(m0 + r) * KIN + k0 + cg * 4];
        float4 bv = *(const float4*)&W[(size_t)(n0 + r) * KIN + k0 + cg * 4];
        __syncthreads();
        As[cg*4+0][r] = av.x; As[cg*4+1][r] = av.y; As[cg*4+2][r] = av.z; As[cg*4+3][r] = av.w;
        Bs[cg*4+0][r] = bv.x; Bs[cg*4+1][r] = bv.y; Bs[cg*4+2][r] = bv.z; Bs[cg*4+3][r] = bv.w;
        __syncthreads();
#pragma unroll
        for (int kk = 0; kk < 16; ++kk) {
            float4 a = *(const float4*)&As[kk][ty * 4];
            float4 b = *(const float4*)&Bs[kk][tx * 4];
            float ar[4] = {a.x, a.y, a.z, a.w};
            float br[4] = {b.x, b.y, b.z, b.w};
#pragma unroll
            for (int i = 0; i < 4; ++i)
#pragma unroll
                for (int j = 0; j < 4; ++j) acc[i][j] += ar[i] * br[j];
        }
    }
    if (n0 < 256) {
#pragma unroll
        for (int i = 0; i < 4; ++i) {
            float4 o = make_float4(acc[i][0], acc[i][1], acc[i][2], acc[i][3]);
            *(float4*)&ik_out[(size_t)(m0 + ty * 4 + i) * 256 + n0 + tx * 4] = o;
        }
    } else {
        const int b  = m0 >> 9;
        const int s0 = (m0 & 511) + ty * 4;
#pragma unroll
        for (int j = 0; j < 4; ++j) {
            float4 o = make_float4(acc[0][j], acc[1][j], acc[2][j], acc[3][j]);
            *(float4*)&iv_t[((size_t)b * H + (n0 - 256 + tx * 4 + j)) * SS + s0] = o;
        }
    }
}

// Per (b, col): scan kv, write key only. 32-deep prefetch.
__global__ __launch_bounds__(64) void key_scan(const float* __restrict__ ik,
                                               float* __restrict__ keys) {
    const int idx = blockIdx.x * 64 + threadIdx.x;   // 0..4095
    const int b   = idx >> 8;
    const int col = idx & 255;
    const float* c  = ik + (size_t)b * SS * 256 + col;
    float* ko = keys + (size_t)b * SS * H + col;
    float kv = 0.f;
    constexpr int D = 32;
    float ib[D];
#pragma unroll
    for (int j = 0; j < D; ++j) ib[j] = c[(size_t)j * 256];
    for (int t = 0; t < SS; t += D) {
#pragma unroll
        for (int j = 0; j < D; ++j) {
            float v = ib[j];
            int tn = t + D + j; if (tn > SS - 1) tn = SS - 1;
            ib[j] = c[(size_t)tn * 256];
            kv = DECAY * kv + v;
            ko[(size_t)(t + j) * H] = fast_tanh(kv);
        }
    }
}

// 2 mem-rows per wave (32 lanes/row, 8 cols/lane). mem-form math, packed f32.
// vals stores batched 16x: lane sub==j captures step t0+j; one masked store
// per 16 steps (kills the per-step scattered-store vmcnt drain).
__global__ __launch_bounds__(256) void value_scan(const float* __restrict__ keys,
                                                  const float* __restrict__ iv_t,
                                                  float* __restrict__ mem_out,
                                                  float* __restrict__ vals) {
    const int tid  = threadIdx.x;
    const int wave = tid >> 6;
    const int lane = tid & 63;
    const int half = lane >> 5;
    const int sub  = lane & 31;
    const int b    = blockIdx.x & 15;     // XCD swizzle: batch-mates share an XCD
    const int rg   = blockIdx.x >> 4;
    const int row  = rg * 8 + wave * 2 + half;
    const int so   = sub * 8;

    const float* kp  = keys + (size_t)b * SS * H + so;       // marching
    const float* ivp = iv_t + ((size_t)b * H + row) * SS;    // marching
    float* vrow = vals + (size_t)b * SS * H + row;           // marching, 16-step batches

    const v2f DEC2 = {DECAY, DECAY};
    const v2f OMD2 = {OMD, OMD};
    const v2f ONE2 = {1.f, 1.f};
    const v2f NM12 = {-1.f, -1.f};

    v2f mem2[4] = {{0.f,0.f},{0.f,0.f},{0.f,0.f},{0.f,0.f}};
    v2f ktr[4]  = {{0.f,0.f},{0.f,0.f},{0.f,0.f},{0.f,0.f}};
    float vv = 0.f, vt = 0.f, stash = 0.f;

    // key ring: 8 steps deep, pair-aligned v2f
    v2f kR[8][4];
#pragma unroll
    for (int j = 0; j < 8; ++j)
#pragma unroll
        for (int q = 0; q < 4; ++q)
            kR[j][q] = *(const v2f*)(kp + (size_t)j * H + q * 2);
    kp += 8 * H;                       // -> step 8

    // iv: current 16 steps in registers
    float4 ivA0 = *(const float4*)(ivp);
    float4 ivA1 = *(const float4*)(ivp + 4);
    float4 ivB0 = *(const float4*)(ivp + 8);
    float4 ivB1 = *(const float4*)(ivp + 12);
    ivp += 16;

#define VS_STEP(J, RELOAD, KOFF)                                               \
    {                                                                          \
        const int SL = (J) & 7;                                                \
        v2f kc0 = kR[SL][0], kc1 = kR[SL][1], kc2 = kR[SL][2], kc3 = kR[SL][3];\
        if (RELOAD) {                                                          \
            kR[SL][0] = *(const v2f*)(kp + (KOFF) * H + 0);                    \
            kR[SL][1] = *(const v2f*)(kp + (KOFF) * H + 2);                    \
            kR[SL][2] = *(const v2f*)(kp + (KOFF) * H + 4);                    \
            kR[SL][3] = *(const v2f*)(kp + (KOFF) * H + 6);                    \
        }                                                                      \
        v2f p2 = pk_mul(mem2[0], kc0);                                         \
        p2 = pk_fma(mem2[1], kc1, p2);                                         \
        p2 = pk_fma(mem2[2], kc2, p2);                                         \
        p2 = pk_fma(mem2[3], kc3, p2);                                         \
        float slo, shi;                                                        \
        half_sum32(p2.x + p2.y, slo, shi);                                     \
        float ps = half ? shi : slo;                                           \
        float civ = ivs[J];                                                    \
        vv = __builtin_fmaf(DECAY, vv, civ);                                   \
        vv = __builtin_fmaf(0.2f, ps, vv);                                     \
        float valv = fast_tanh(vv);                                            \
        vt = __builtin_fmaf(DECAY, vt, OMD * valv);                            \
        if (sub == (J)) stash = valv;                                          \
        float c = LR * vt;                                                     \
        v2f c2 = {c, c};                                                       \
        ktr[0] = pk_fma(DEC2, ktr[0], pk_mul(OMD2, kc0));                      \
        ktr[1] = pk_fma(DEC2, ktr[1], pk_mul(OMD2, kc1));                      \
        ktr[2] = pk_fma(DEC2, ktr[2], pk_mul(OMD2, kc2));                      \
        ktr[3] = pk_fma(DEC2, ktr[3], pk_mul(OMD2, kc3));                      \
        v2f d0 = pk_fma(mem2[0], NM12, ONE2);                                  \
        v2f d1 = pk_fma(mem2[1], NM12, ONE2);                                  \
        v2f d2 = pk_fma(mem2[2], NM12, ONE2);                                  \
        v2f d3 = pk_fma(mem2[3], NM12, ONE2);                                  \
        mem2[0] = pk_fma(pk_mul(c2, ktr[0]), d0, mem2[0]);                     \
        mem2[1] = pk_fma(pk_mul(c2, ktr[1]), d1, mem2[1]);                     \
        mem2[2] = pk_fma(pk_mul(c2, ktr[2]), d2, mem2[2]);                     \
        mem2[3] = pk_fma(pk_mul(c2, ktr[3]), d3, mem2[3]);                     \
    }

#define VS_TILE16(RELOAD_A, RELOAD_B)                                          \
    {                                                                          \
        float ivs[16] = {ivA0.x, ivA0.y, ivA0.z, ivA0.w,                       \
                         ivA1.x, ivA1.y, ivA1.z, ivA1.w,                       \
                         ivB0.x, ivB0.y, ivB0.z, ivB0.w,                       \
                         ivB1.x, ivB1.y, ivB1.z, ivB1.w};                      \
        VS_STEP(0, RELOAD_A, 0) VS_STEP(1, RELOAD_A, 1)                        \
        VS_STEP(2, RELOAD_A, 2) VS_STEP(3, RELOAD_A, 3)                        \
        if (RELOAD_A) kp += 4 * H;                                             \
        VS_STEP(4, RELOAD_A, 0) VS_STEP(5, RELOAD_A, 1)                        \
        VS_STEP(6, RELOAD_A, 2) VS_STEP(7, RELOAD_A, 3)                        \
        if (RELOAD_A) kp += 4 * H;                                             \
        VS_STEP(8, RELOAD_B, 0) VS_STEP(9, RELOAD_B, 1)                        \
        VS_STEP(10, RELOAD_B, 2) VS_STEP(11, RELOAD_B, 3)                      \
        if (RELOAD_B) kp += 4 * H;                                             \
        VS_STEP(12, RELOAD_B, 0) VS_STEP(13, RELOAD_B, 1)                      \
        VS_STEP(14, RELOAD_B, 2) VS_STEP(15, RELOAD_B, 3)                      \
        if (RELOAD_B) kp += 4 * H;                                             \
        if (sub < 16) vrow[(size_t)sub * H] = stash;                           \
        vrow += 16 * H;                                                        \
    }

    // main: tiles t0 = 0..480 (ring reload fetches <= 503, iv prefetch <= 511)
    for (int t0 = 0; t0 < SS - 16; t0 += 16) {
        float4 nA0 = *(const float4*)(ivp);
        float4 nA1 = *(const float4*)(ivp + 4);
        float4 nB0 = *(const float4*)(ivp + 8);
        float4 nB1 = *(const float4*)(ivp + 12);
        ivp += 16;
        VS_TILE16(true, true)
        ivA0 = nA0; ivA1 = nA1; ivB0 = nB0; ivB1 = nB1;
    }
    // epilogue tile t0 = 496: steps 496-503 reload (fetch 504-511), 504-511 don't
    VS_TILE16(true, false)
#undef VS_TILE16
#undef VS_STEP

    float* mo = &mem_out[((size_t)b * H + row) * H + so];
    *(float4*)&mo[0] = make_float4(mem2[0].x, mem2[0].y, mem2[1].x, mem2[1].y);
    *(float4*)&mo[4] = make_float4(mem2[2].x, mem2[2].y, mem2[3].x, mem2[3].y);
}

extern "C" void kernel_launch(void* const* d_in, const int* in_sizes, int n_in,
                              void* d_out, int out_size, void* d_ws, size_t ws_size,
                              hipStream_t stream) {
    const float* x = (const float*)d_in[0];   // [B, S, IN] f32
    const float* W = (const float*)d_in[1];   // [2H, IN] f32
    float* out = (float*)d_out;
    float* mem_out = out;                               // [B, H, H]
    float* keys = out + (size_t)BB * H * H;             // [B, S, H]
    float* vals = keys + (size_t)BB * SS * H;           // [B, S, H]
    float* ik   = (float*)d_ws;                         // [B*S, 256]  8 MB
    float* iv_t = ik + (size_t)BB * SS * 256;           // [B, H, S]   8 MB

    dim3 gb(8, 128);  // N/64, M/64
    gemm_xwT<<<gb, 256, 0, stream>>>(x, W, ik, iv_t);
    key_scan<<<64, 64, 0, stream>>>(ik, keys);
    value_scan<<<512, 256, 0, stream>>>(keys, iv_t, mem_out, vals);
}